// Round 4
// baseline (203.120 us; speedup 1.0000x reference)
//
#include <hip/hip_runtime.h>

// Cosine-similarity attention context:
//   dots[s]  = keys[s,:] . q
//   cos[s]   = dots[s] / (||q|| * ||keys[s,:]||)
//   ctx[h]   = sum_s cos[s] * keys[s,h]
// keys = 32768 x 1024 f32 (128 MiB) -> single streaming pass, BW-bound.
//
// R3 -> R4: total (196us) is harness-dominated (512MiB ws poison ~77us +
// keys restore ~40us). Controllable slice = main kernel. R3 ran only
// 2 blocks/CU (8 waves/CU); VGPR=44 / LDS=16KiB allow 8 blocks/CU. Raise
// grid to 2048 for 4x outstanding loads -> push streaming toward the
// ~12us mixed L3/HBM floor. Reduce kernel upgraded to float4 (8 MiB now).

constexpr int H   = 1024;   // hidden dim (fixed by problem)
constexpr int TPB = 256;    // 4 waves per block
constexpr int WPB = TPB / 64;
constexpr int NBLOCKS = 2048;   // 8 blocks/CU -> 32 waves/CU (occupancy max)

__global__ __launch_bounds__(TPB, 4)
void cosctx_main(const float* __restrict__ q,
                 const float* __restrict__ keys,
                 int S,
                 float* __restrict__ ws)
{
    const int lane  = threadIdx.x & 63;
    const int wave  = threadIdx.x >> 6;
    const int gwave = blockIdx.x * WPB + wave;
    const int nwaves = gridDim.x * WPB;

    const float4* q4 = reinterpret_cast<const float4*>(q);
    const float4* k4 = reinterpret_cast<const float4*>(keys);

    // --- query fragment + 1/||q|| (redundant per wave; q is 4 KiB, L2-hot) ---
    float4 qv[4];
#pragma unroll
    for (int j = 0; j < 4; ++j) qv[j] = q4[j * 64 + lane];

    float qsq = 0.f;
#pragma unroll
    for (int j = 0; j < 4; ++j)
        qsq += qv[j].x * qv[j].x + qv[j].y * qv[j].y +
               qv[j].z * qv[j].z + qv[j].w * qv[j].w;
#pragma unroll
    for (int off = 32; off > 0; off >>= 1) qsq += __shfl_down(qsq, off, 64);
    const float inv_qn = rsqrtf(__shfl(qsq, 0, 64));

    float4 acc[4];
#pragma unroll
    for (int j = 0; j < 4; ++j) acc[j] = make_float4(0.f, 0.f, 0.f, 0.f);

    // --- single pass over rows, 1-row prefetch pipeline (4 rows/wave) ---
    int row = gwave;
    float4 kv[4];
    if (row < S) {
        const float4* kr = k4 + (size_t)row * (H / 4);
#pragma unroll
        for (int j = 0; j < 4; ++j) kv[j] = kr[j * 64 + lane];
    }
    while (row < S) {
        const int nrow = row + nwaves;
        float4 kn[4];
        if (nrow < S) {
            const float4* kr = k4 + (size_t)nrow * (H / 4);
#pragma unroll
            for (int j = 0; j < 4; ++j) kn[j] = kr[j * 64 + lane];
        }

        float dot = 0.f, ksq = 0.f;
#pragma unroll
        for (int j = 0; j < 4; ++j) {
            dot += kv[j].x * qv[j].x + kv[j].y * qv[j].y +
                   kv[j].z * qv[j].z + kv[j].w * qv[j].w;
            ksq += kv[j].x * kv[j].x + kv[j].y * kv[j].y +
                   kv[j].z * kv[j].z + kv[j].w * kv[j].w;
        }
        // two interleaved (independent) shuffle-reduce chains, no barriers
#pragma unroll
        for (int off = 32; off > 0; off >>= 1) {
            dot += __shfl_down(dot, off, 64);
            ksq += __shfl_down(ksq, off, 64);
        }
        const float score = __shfl(dot, 0, 64) * inv_qn *
                            rsqrtf(__shfl(ksq, 0, 64));

#pragma unroll
        for (int j = 0; j < 4; ++j) {
            acc[j].x += score * kv[j].x;
            acc[j].y += score * kv[j].y;
            acc[j].z += score * kv[j].z;
            acc[j].w += score * kv[j].w;
        }
#pragma unroll
        for (int j = 0; j < 4; ++j) kv[j] = kn[j];
        row = nrow;
    }

    // --- block reduce: 4 wave-partials -> 1 block-partial [H] ---
    __shared__ float sacc[WPB][H];   // 16 KiB
    float4* sa4 = reinterpret_cast<float4*>(sacc[wave]);
#pragma unroll
    for (int j = 0; j < 4; ++j) sa4[j * 64 + lane] = acc[j];
    __syncthreads();

    float4 v = make_float4(0.f, 0.f, 0.f, 0.f);
#pragma unroll
    for (int w = 0; w < WPB; ++w) {
        float4 u = reinterpret_cast<const float4*>(sacc[w])[threadIdx.x];
        v.x += u.x; v.y += u.y; v.z += u.z; v.w += u.w;
    }

    // block-partial to workspace, plain store (no atomics anywhere)
    reinterpret_cast<float4*>(ws)[(size_t)blockIdx.x * (H / 4) + threadIdx.x] = v;
}

// Sum NBLOCKS x H block-partials (8 MiB) -> out. Atomic-free, float4 loads.
// 16 blocks; block b owns 16 float4-cols (64 scalar cols). 256 threads =
// 16 cols x 16 row-chunks of 128 rows; LDS tree over chunks; 16 lanes store.
__global__ __launch_bounds__(TPB)
void cosctx_reduce(const float* __restrict__ ws, float* __restrict__ out)
{
    const float4* ws4 = reinterpret_cast<const float4*>(ws);
    const int c     = threadIdx.x & 15;            // col within block
    const int chunk = threadIdx.x >> 4;            // 0..15
    const int col4  = blockIdx.x * 16 + c;
    const int rpc   = NBLOCKS / 16;                // 128 rows per chunk

    float4 s = make_float4(0.f, 0.f, 0.f, 0.f);
#pragma unroll 4
    for (int r = chunk * rpc; r < (chunk + 1) * rpc; ++r) {
        float4 u = ws4[(size_t)r * (H / 4) + col4];
        s.x += u.x; s.y += u.y; s.z += u.z; s.w += u.w;
    }

    __shared__ float4 red[16][16];   // 4 KiB
    red[chunk][c] = s;
    __syncthreads();

#pragma unroll
    for (int h = 8; h > 0; h >>= 1) {
        if (chunk < h) {
            float4 a = red[chunk][c], b = red[chunk + h][c];
            a.x += b.x; a.y += b.y; a.z += b.z; a.w += b.w;
            red[chunk][c] = a;
        }
        __syncthreads();
    }

    if (threadIdx.x < 16)
        reinterpret_cast<float4*>(out)[blockIdx.x * 16 + threadIdx.x] =
            red[0][threadIdx.x];
}

extern "C" void kernel_launch(void* const* d_in, const int* in_sizes, int n_in,
                              void* d_out, int out_size, void* d_ws, size_t ws_size,
                              hipStream_t stream)
{
    const float* q    = (const float*)d_in[0];
    const float* keys = (const float*)d_in[1];
    float* out        = (float*)d_out;
    const int S = in_sizes[1] / H;

    // 2-node graph, zero atomics: main -> reduce (reduce fully writes out).
    // ws need = NBLOCKS*H*4 = 8 MiB; harness ws is 512 MiB.
    cosctx_main<<<NBLOCKS, TPB, 0, stream>>>(q, keys, S, (float*)d_ws);
    cosctx_reduce<<<H / 64, TPB, 0, stream>>>((const float*)d_ws, out);
}